// Round 1
// baseline (5942.307 us; speedup 1.0000x reference)
//
#include <hip/hip_runtime.h>

// Problem constants: B=4, T=8, H=W=16, C=F=256, gates=4F=1024.
#define HW      256     // 16*16 pixels per image
#define CIN     256
#define COUT    1024
#define TSTEPS  8
#define BN_EPS  1e-3f

// ---------------------------------------------------------------------------
// conv3x3: SAME-padded 3x3 conv, Cin=256 -> Cout=1024, NHWC / HWIO.
// One block: one image row (16 px) x (ntpb*256) output channels.
// 3 input rows (y-1..y+1) staged in LDS, width padded to 18 with zeros.
// Thread t: wave p=t>>6 owns pixels {p, p+4, p+8, p+12}; lane owns 4 channels.
// All compute-loop LDS reads are wave-uniform (broadcast, conflict-free);
// weight reads are per-wave contiguous 1KB float4 (L1/L2 served).
// ---------------------------------------------------------------------------
__global__ __launch_bounds__(256) void conv3x3_k(
    const float* __restrict__ in,     // (nimg, 16, 16, 256)
    const float* __restrict__ w,      // (3, 3, 256, 1024)
    const float* __restrict__ bias,   // (1024) or nullptr
    const float* __restrict__ add,    // per-image add source or nullptr
    long add_stride,                  // floats between images in `add`
    float* __restrict__ out,          // (nimg, 16, 16, 1024)
    long out_stride,                  // floats between images in `out`
    long in_stride,                   // floats between images in `in`
    int ntpb)                         // n-tiles (of 256 ch) per block
{
    __shared__ float lds[3 * 18 * 256];
    const int tid = threadIdx.x;
    const int nNT = 4 / ntpb;
    const int bid = blockIdx.x;
    const int img = bid / (16 * nNT);
    const int r0  = bid % (16 * nNT);
    const int y   = r0 / nNT;
    const int nt0 = (r0 % nNT) * ntpb;

    const float4 z4 = make_float4(0.f, 0.f, 0.f, 0.f);

    // zero-pad columns 0 and 17 of each of the 3 rows (3*2*64 float4)
    for (int i = tid; i < 3 * 2 * 64; i += 256) {
        int r = i / 128; int side = (i >> 6) & 1; int c4 = i & 63;
        ((float4*)lds)[(r * 18 + (side ? 17 : 0)) * 64 + c4] = z4;
    }
    // stage rows y-1..y+1 into column slots 1..16 (3*16*64 float4)
    for (int i = tid; i < 3 * 16 * 64; i += 256) {
        int c4 = i & 63; int xx = (i >> 6) & 15; int r = i >> 10;
        int gy = y + r - 1;
        float4 v = z4;
        if (gy >= 0 && gy < 16)
            v = *(const float4*)(in + (long)img * in_stride + ((long)gy * 16 + xx) * CIN + c4 * 4);
        ((float4*)lds)[(r * 18 + xx + 1) * 64 + c4] = v;
    }
    __syncthreads();

    const int p  = tid >> 6;          // wave id -> pixel group
    const int nl = (tid & 63) * 4;    // channel offset within 256-wide tile

    for (int nt = nt0; nt < nt0 + ntpb; ++nt) {
        const int n = nt * 256 + nl;
        float acc[4][4];
        #pragma unroll
        for (int i = 0; i < 4; ++i)
            #pragma unroll
            for (int j = 0; j < 4; ++j) acc[i][j] = 0.f;

        for (int dy = 0; dy < 3; ++dy) {
            for (int dx = 0; dx < 3; ++dx) {
                const float* wb = w + ((long)(dy * 3 + dx) * CIN) * COUT + n;
                const float* ib = lds + (dy * 18 + dx) * 256;
                for (int c = 0; c < 256; c += 4) {
                    float4 w0 = *(const float4*)(wb + (long)(c + 0) * COUT);
                    float4 w1 = *(const float4*)(wb + (long)(c + 1) * COUT);
                    float4 w2 = *(const float4*)(wb + (long)(c + 2) * COUT);
                    float4 w3 = *(const float4*)(wb + (long)(c + 3) * COUT);
                    #pragma unroll
                    for (int i = 0; i < 4; ++i) {
                        const int xx = p + 4 * i;
                        float4 iv = *(const float4*)(ib + xx * 256 + c);
                        acc[i][0] += iv.x * w0.x + iv.y * w1.x + iv.z * w2.x + iv.w * w3.x;
                        acc[i][1] += iv.x * w0.y + iv.y * w1.y + iv.z * w2.y + iv.w * w3.y;
                        acc[i][2] += iv.x * w0.z + iv.y * w1.z + iv.z * w2.z + iv.w * w3.z;
                        acc[i][3] += iv.x * w0.w + iv.y * w1.w + iv.z * w2.w + iv.w * w3.w;
                    }
                }
            }
        }

        float4 bv = z4;
        if (bias) bv = *(const float4*)(bias + n);
        #pragma unroll
        for (int i = 0; i < 4; ++i) {
            const int xx = p + 4 * i;
            const long po = (long)y * 16 + xx;
            float4 av = z4;
            if (add) av = *(const float4*)(add + (long)img * add_stride + po * COUT + n);
            float4 r;
            r.x = acc[i][0] + bv.x + av.x;
            r.y = acc[i][1] + bv.y + av.y;
            r.z = acc[i][2] + bv.z + av.z;
            r.w = acc[i][3] + bv.w + av.w;
            *(float4*)(out + (long)img * out_stride + po * COUT + n) = r;
        }
    }
}

// ---------------------------------------------------------------------------
// gates: g (4 imgs, 256 px, 1024) + c_prev -> c, h; h also scattered into hs.
// Keras gate order i,f,c,o; recurrent_activation = hard_sigmoid.
// ---------------------------------------------------------------------------
__global__ __launch_bounds__(256) void gates_k(
    const float* __restrict__ g, float* __restrict__ cbuf,
    float* __restrict__ hbuf, float* __restrict__ hs, int t)
{
    const int idx = blockIdx.x * 256 + threadIdx.x;   // 0 .. 262143
    const int f   = idx & 255;
    const int pix = (idx >> 8) & 255;
    const int b   = idx >> 16;
    const long base = ((long)(b * 256 + pix)) * 1024;
    float ig = g[base + f];
    float fg = g[base + 256 + f];
    float cc = g[base + 512 + f];
    float og = g[base + 768 + f];
    ig = fminf(fmaxf(0.2f * ig + 0.5f, 0.f), 1.f);
    fg = fminf(fmaxf(0.2f * fg + 0.5f, 0.f), 1.f);
    og = fminf(fmaxf(0.2f * og + 0.5f, 0.f), 1.f);
    float c = fg * cbuf[idx] + ig * tanhf(cc);
    float h = og * tanhf(c);
    cbuf[idx] = c;
    hbuf[idx] = h;
    hs[((long)(b * TSTEPS + t)) * HW * 256 + (long)pix * 256 + f] = h;
}

// ---------------------------------------------------------------------------
// BN (training mode): mean/var over (B,T,H,W) per channel, then affine.
// Deterministic two-stage reduction (no float atomics).
// ---------------------------------------------------------------------------
__global__ __launch_bounds__(256) void bn_stats1_k(
    const float* __restrict__ x, float* __restrict__ partial)
{
    const int tid = threadIdx.x;          // == channel
    const int blk = blockIdx.x;           // 512 blocks x 16 groups of 256
    float s = 0.f, s2 = 0.f;
    const long base = (long)blk * 16 * 256;
    #pragma unroll
    for (int gi = 0; gi < 16; ++gi) {
        float v = x[base + gi * 256 + tid];
        s += v; s2 += v * v;
    }
    partial[blk * 512 + tid]       = s;
    partial[blk * 512 + 256 + tid] = s2;
}

__global__ __launch_bounds__(256) void bn_stats2_k(
    const float* __restrict__ partial, const float* __restrict__ gamma,
    const float* __restrict__ beta, float* __restrict__ stats)
{
    const int f = threadIdx.x;
    float s = 0.f, s2 = 0.f;
    for (int b = 0; b < 512; ++b) {
        s  += partial[b * 512 + f];
        s2 += partial[b * 512 + 256 + f];
    }
    const float inv_n = 1.f / 8192.f;
    float mu  = s * inv_n;
    float var = s2 * inv_n - mu * mu;
    float sc  = gamma[f] * rsqrtf(var + BN_EPS);
    stats[f]       = sc;
    stats[256 + f] = beta[f] - mu * sc;
}

__global__ __launch_bounds__(256) void bn_apply_k(
    const float* __restrict__ x, const float* __restrict__ stats,
    float* __restrict__ y)
{
    const int q  = blockIdx.x * 256 + threadIdx.x;   // float4 index
    const int ch = (q & 63) * 4;
    float4 v  = ((const float4*)x)[q];
    float4 sc = *(const float4*)(stats + ch);
    float4 sh = *(const float4*)(stats + 256 + ch);
    float4 r;
    r.x = v.x * sc.x + sh.x;
    r.y = v.y * sc.y + sh.y;
    r.z = v.z * sc.z + sh.z;
    r.w = v.w * sc.w + sh.w;
    ((float4*)y)[q] = r;
}

// ---------------------------------------------------------------------------
extern "C" void kernel_launch(void* const* d_in, const int* in_sizes, int n_in,
                              void* d_out, int out_size, void* d_ws, size_t ws_size,
                              hipStream_t stream)
{
    const float* x0    = (const float*)d_in[0];
    const float* Wx[3] = {(const float*)d_in[1], (const float*)d_in[6],  (const float*)d_in[11]};
    const float* Wh[3] = {(const float*)d_in[2], (const float*)d_in[7],  (const float*)d_in[12]};
    const float* bb[3] = {(const float*)d_in[3], (const float*)d_in[8],  (const float*)d_in[13]};
    const float* gg[3] = {(const float*)d_in[4], (const float*)d_in[9],  (const float*)d_in[14]};
    const float* be[3] = {(const float*)d_in[5], (const float*)d_in[10], (const float*)d_in[15]};

    float* ws    = (float*)d_ws;
    float* xg    = ws;                  // 32*256*1024  = 8,388,608
    float* gtmp  = xg   + 8388608;      // 4*256*1024   = 1,048,576
    float* hbuf  = gtmp + 1048576;      // 4*256*256    =   262,144
    float* cbuf  = hbuf + 262144;       //                  262,144
    float* hsb   = cbuf + 262144;       // 4*8*256*256  = 2,097,152
    float* xbuf  = hsb  + 2097152;      //                2,097,152
    float* part  = xbuf + 2097152;      // 512*512      =   262,144
    float* stats = part + 262144;       //                      512
    // total ~57.7 MB of workspace

    const float* lin = x0;
    for (int l = 0; l < 3; ++l) {
        // 1) input-to-gate conv for all 32 (b,t) images: xg = conv(x, Wx) + b
        hipLaunchKernelGGL(conv3x3_k, dim3(512), dim3(256), 0, stream,
            lin, Wx[l], bb[l], (const float*)nullptr, 0L,
            xg, (long)(HW * COUT), (long)(HW * CIN), 4);

        hipMemsetAsync(hbuf, 0, 262144 * sizeof(float), stream);
        hipMemsetAsync(cbuf, 0, 262144 * sizeof(float), stream);

        // 2) recurrence over T
        for (int t = 0; t < TSTEPS; ++t) {
            hipLaunchKernelGGL(conv3x3_k, dim3(256), dim3(256), 0, stream,
                hbuf, Wh[l], (const float*)nullptr,
                xg + (long)t * HW * COUT, (long)TSTEPS * HW * COUT,
                gtmp, (long)(HW * COUT), (long)(HW * CIN), 1);
            hipLaunchKernelGGL(gates_k, dim3(1024), dim3(256), 0, stream,
                gtmp, cbuf, hbuf, hsb, t);
        }

        // 3) BatchNorm (training stats) -> next-layer input (or d_out)
        float* dst = (l == 2) ? (float*)d_out : xbuf;
        hipLaunchKernelGGL(bn_stats1_k, dim3(512), dim3(256), 0, stream, hsb, part);
        hipLaunchKernelGGL(bn_stats2_k, dim3(1), dim3(256), 0, stream, part, gg[l], be[l], stats);
        hipLaunchKernelGGL(bn_apply_k, dim3(2048), dim3(256), 0, stream, hsb, stats, dst);
        lin = xbuf;
    }
}

// Round 3
// 995.794 us; speedup vs baseline: 5.9674x; 5.9674x over previous
//
#include <hip/hip_runtime.h>

// B=4, T=8, H=W=16, C=F=256, gates 4F=1024. K = 9*256 = 2304.
// Round 3: same implicit-GEMM MFMA structure as round 2 but FP16 operands
// (same MFMA rate as bf16, 8x lower quantization error; all quantized
// tensors bounded well inside fp16 range).
#define HW      256
#define COUT    1024
#define TSTEPS  8
#define BN_EPS  1e-3f
#define KTOT    2304
#define KQN     72          // KTOT/32

typedef unsigned short u16;
typedef unsigned int   u32;
typedef __attribute__((ext_vector_type(8))) _Float16 v8h;  // 8 x fp16 (4 VGPRs)
typedef __attribute__((ext_vector_type(4))) float v4f;

__device__ __forceinline__ u16 f2h(float x) {
    _Float16 h = (_Float16)x;          // v_cvt_f16_f32, RTNE
    return *(u16*)&h;
}

typedef __attribute__((address_space(1))) const unsigned int gas_u32;
typedef __attribute__((address_space(3))) unsigned int las_u32;
__device__ __forceinline__ void gl16(const void* g, void* l) {
    __builtin_amdgcn_global_load_lds((gas_u32*)g, (las_u32*)l, 16, 0, 0);
}

// ---------------------------------------------------------------------------
// Implicit-GEMM fp16 conv: out[m][n] = sum_k apad[pixel(m)+shift(k)][c(k)] * wT[n][k]
// apad: (nimg,18,18,256) fp16 zero-padded activations. wT: (1024,2304) fp16.
// m97 structure: BK=32, global_load_lds(16B), 2-barrier K-loop, 4 waves (2x2).
// ---------------------------------------------------------------------------
template<int BM, int BN, int SWZ>
__global__ __launch_bounds__(256) void conv_mfma_k(
    const u16* __restrict__ apad, const u16* __restrict__ wT,
    const float* __restrict__ bias, const float* __restrict__ add,
    long add_img_stride, float* __restrict__ out)
{
    constexpr int AR  = BM / 4;        // A rows staged per wave
    constexpr int BR  = BN / 4;
    constexpr int ANI = AR / 16;       // global_load_lds instrs per wave
    constexpr int BNI = BR / 16;
    constexpr int MI  = BM / 32;       // 16x16 frags per wave (rows)
    constexpr int NI  = BN / 32;

    __shared__ u16 Alds[BM * 32];
    __shared__ u16 Blds[BN * 32];

    int bx, by;
    if (SWZ) {  // recurrent conv: group n-slices per XCD (bid%8 round-robin)
        int bid = blockIdx.x;
        int k8 = bid & 7, q = bid >> 3;
        by = 2 * k8 + (q >> 4);
        bx = q & 15;
    } else { bx = blockIdx.x; by = blockIdx.y; }

    const int m0 = bx * BM, n0 = by * BN;
    const int tid = threadIdx.x, lane = tid & 63, w = tid >> 6;
    const int wr = w >> 1, wc = w & 1;

    // per-lane staging source base addresses (bytes)
    const char* a_src[ANI];
    #pragma unroll
    for (int i = 0; i < ANI; ++i) {
        int m = m0 + w * AR + i * 16 + (lane >> 2);
        int img = m >> 8, pix = m & 255;
        int yy = pix >> 4, xx = pix & 15;
        a_src[i] = (const char*)apad +
                   ((((long)img * 18 + yy) * 18 + xx) * 256) * 2 + (lane & 3) * 16;
    }
    const char* b_src[BNI];
    #pragma unroll
    for (int i = 0; i < BNI; ++i) {
        int n = n0 + w * BR + i * 16 + (lane >> 2);
        b_src[i] = (const char*)wT + ((long)n * KTOT) * 2 + (lane & 3) * 16;
    }

    v4f acc[MI][NI];
    #pragma unroll
    for (int mi = 0; mi < MI; ++mi)
        #pragma unroll
        for (int ni = 0; ni < NI; ++ni) acc[mi][ni] = (v4f)0.f;

    for (int kq = 0; kq < KQN; ++kq) {
        int dxy = kq >> 3, c32 = kq & 7;
        int dy = (dxy * 11) >> 5;          // /3 for 0..8
        int dx = dxy - dy * 3;
        int aoff = ((dy * 18 + dx) * 256 + c32 * 32) * 2;   // bytes
        int boff = kq * 64;
        #pragma unroll
        for (int i = 0; i < ANI; ++i)
            gl16(a_src[i] + aoff, (char*)Alds + (w * AR + i * 16) * 64);
        #pragma unroll
        for (int i = 0; i < BNI; ++i)
            gl16(b_src[i] + boff, (char*)Blds + (w * BR + i * 16) * 64);
        __syncthreads();

        v8h af[MI], bf[NI];
        #pragma unroll
        for (int mi = 0; mi < MI; ++mi)
            af[mi] = *(const v8h*)&Alds[(wr * (BM / 2) + mi * 16 + (lane & 15)) * 32 + (lane >> 4) * 8];
        #pragma unroll
        for (int ni = 0; ni < NI; ++ni)
            bf[ni] = *(const v8h*)&Blds[(wc * (BN / 2) + ni * 16 + (lane & 15)) * 32 + (lane >> 4) * 8];
        #pragma unroll
        for (int mi = 0; mi < MI; ++mi)
            #pragma unroll
            for (int ni = 0; ni < NI; ++ni)
                acc[mi][ni] = __builtin_amdgcn_mfma_f32_16x16x32_f16(af[mi], bf[ni], acc[mi][ni], 0, 0, 0);
        __syncthreads();
    }

    // epilogue: +bias, +add (fp32), store fp32 (m,1024)
    #pragma unroll
    for (int mi = 0; mi < MI; ++mi) {
        #pragma unroll
        for (int ni = 0; ni < NI; ++ni) {
            int mrow = m0 + wr * (BM / 2) + mi * 16 + ((lane >> 4) << 2);
            int ncol = n0 + wc * (BN / 2) + ni * 16 + (lane & 15);
            float b0 = bias ? bias[ncol] : 0.f;
            #pragma unroll
            for (int r = 0; r < 4; ++r) {
                int m = mrow + r;
                float v = acc[mi][ni][r] + b0;
                if (add)
                    v += add[(long)(m >> 8) * add_img_stride + (long)(m & 255) * COUT + ncol];
                out[(long)m * COUT + ncol] = v;
            }
        }
    }
}

// ---------------------------------------------------------------------------
// weight prep: w (3,3,256,1024) fp32 -> wT (1024,2304) fp16 (transposed)
// ---------------------------------------------------------------------------
__global__ __launch_bounds__(256) void wprep_k(const float* __restrict__ w,
                                               u16* __restrict__ wT)
{
    int k0 = blockIdx.x * 32;
    int n  = blockIdx.y * 256 + threadIdx.x;
    u32 pk[16];
    #pragma unroll
    for (int kk = 0; kk < 32; kk += 2) {
        float a = w[(long)(k0 + kk) * COUT + n];
        float b = w[(long)(k0 + kk + 1) * COUT + n];
        pk[kk >> 1] = (u32)f2h(a) | ((u32)f2h(b) << 16);
    }
    uint4* dst = (uint4*)&wT[(long)n * KTOT + k0];
    dst[0] = make_uint4(pk[0], pk[1], pk[2], pk[3]);
    dst[1] = make_uint4(pk[4], pk[5], pk[6], pk[7]);
    dst[2] = make_uint4(pk[8], pk[9], pk[10], pk[11]);
    dst[3] = make_uint4(pk[12], pk[13], pk[14], pk[15]);
}

// ---------------------------------------------------------------------------
// convert input x (32,16,16,256) fp32 -> pad_x interior fp16
// ---------------------------------------------------------------------------
__global__ __launch_bounds__(256) void convert_x_k(const float* __restrict__ x,
                                                   u16* __restrict__ padx)
{
    int q = blockIdx.x * 256 + threadIdx.x;     // float4 index, 524288 total
    int e0 = q * 4;
    int f = e0 & 255, pix = (e0 >> 8) & 255, img = e0 >> 16;
    float4 v = ((const float4*)x)[q];
    int yy = pix >> 4, xx = pix & 15;
    long o = (((long)img * 18 + yy + 1) * 18 + xx + 1) * 256 + f;
    u32 lo = (u32)f2h(v.x) | ((u32)f2h(v.y) << 16);
    u32 hi = (u32)f2h(v.z) | ((u32)f2h(v.w) << 16);
    *(uint2*)&padx[o] = make_uint2(lo, hi);
}

// ---------------------------------------------------------------------------
// gates: g=(4,256,1024) preact -> c update, h -> pad_h (fp16) + hs (fp32)
// ---------------------------------------------------------------------------
__global__ __launch_bounds__(256) void gates_k(
    const float* __restrict__ g, float* __restrict__ cbuf,
    float* __restrict__ hs, u16* __restrict__ padh, int t)
{
    const int idx = blockIdx.x * 256 + threadIdx.x;   // 0..262143
    const int f   = idx & 255;
    const int pix = (idx >> 8) & 255;
    const int b   = idx >> 16;
    const long base = ((long)(b * 256 + pix)) * 1024;
    float ig = g[base + f];
    float fg = g[base + 256 + f];
    float cc = g[base + 512 + f];
    float og = g[base + 768 + f];
    ig = fminf(fmaxf(0.2f * ig + 0.5f, 0.f), 1.f);
    fg = fminf(fmaxf(0.2f * fg + 0.5f, 0.f), 1.f);
    og = fminf(fmaxf(0.2f * og + 0.5f, 0.f), 1.f);
    float c = fg * cbuf[idx] + ig * tanhf(cc);
    float h = og * tanhf(c);
    cbuf[idx] = c;
    hs[((long)(b * TSTEPS + t)) * HW * 256 + (long)pix * 256 + f] = h;
    int yy = pix >> 4, xx = pix & 15;
    padh[(((long)b * 18 + yy + 1) * 18 + xx + 1) * 256 + f] = f2h(h);
}

// ---------------------------------------------------------------------------
// BatchNorm: deterministic two-stage stats + apply
// ---------------------------------------------------------------------------
__global__ __launch_bounds__(256) void bn_stats1_k(
    const float* __restrict__ x, float* __restrict__ partial)
{
    const int tid = threadIdx.x;
    const int blk = blockIdx.x;
    float s = 0.f, s2 = 0.f;
    const long base = (long)blk * 16 * 256;
    #pragma unroll
    for (int gi = 0; gi < 16; ++gi) {
        float v = x[base + gi * 256 + tid];
        s += v; s2 += v * v;
    }
    partial[blk * 512 + tid]       = s;
    partial[blk * 512 + 256 + tid] = s2;
}

__global__ __launch_bounds__(256) void bn_stats2_k(
    const float* __restrict__ partial, const float* __restrict__ gamma,
    const float* __restrict__ beta, float* __restrict__ stats)
{
    const int f = threadIdx.x;
    float s = 0.f, s2 = 0.f;
    for (int b = 0; b < 512; ++b) {
        s  += partial[b * 512 + f];
        s2 += partial[b * 512 + 256 + f];
    }
    const float inv_n = 1.f / 8192.f;
    float mu  = s * inv_n;
    float var = s2 * inv_n - mu * mu;
    float sc  = gamma[f] * rsqrtf(var + BN_EPS);
    stats[f]       = sc;
    stats[256 + f] = beta[f] - mu * sc;
}

// writes fp16 into pad_x interior (layers 0,1) or fp32 to d_out (layer 2)
__global__ __launch_bounds__(256) void bn_apply_k(
    const float* __restrict__ x, const float* __restrict__ stats,
    u16* __restrict__ padx, float* __restrict__ out)
{
    const int q = blockIdx.x * 256 + threadIdx.x;   // float4 index
    const int e0 = q * 4;
    const int f = e0 & 255, pix = (e0 >> 8) & 255, img = e0 >> 16;
    float4 v  = ((const float4*)x)[q];
    float4 sc = *(const float4*)(stats + f);
    float4 sh = *(const float4*)(stats + 256 + f);
    v.x = v.x * sc.x + sh.x;
    v.y = v.y * sc.y + sh.y;
    v.z = v.z * sc.z + sh.z;
    v.w = v.w * sc.w + sh.w;
    if (out) ((float4*)out)[q] = v;
    if (padx) {
        int yy = pix >> 4, xx = pix & 15;
        long o = (((long)img * 18 + yy + 1) * 18 + xx + 1) * 256 + f;
        u32 lo = (u32)f2h(v.x) | ((u32)f2h(v.y) << 16);
        u32 hi = (u32)f2h(v.z) | ((u32)f2h(v.w) << 16);
        *(uint2*)&padx[o] = make_uint2(lo, hi);
    }
}

// ---------------------------------------------------------------------------
extern "C" void kernel_launch(void* const* d_in, const int* in_sizes, int n_in,
                              void* d_out, int out_size, void* d_ws, size_t ws_size,
                              hipStream_t stream)
{
    const float* x0    = (const float*)d_in[0];
    const float* Wx[3] = {(const float*)d_in[1], (const float*)d_in[6],  (const float*)d_in[11]};
    const float* Wh[3] = {(const float*)d_in[2], (const float*)d_in[7],  (const float*)d_in[12]};
    const float* bb[3] = {(const float*)d_in[3], (const float*)d_in[8],  (const float*)d_in[13]};
    const float* gg[3] = {(const float*)d_in[4], (const float*)d_in[9],  (const float*)d_in[14]};
    const float* be[3] = {(const float*)d_in[5], (const float*)d_in[10], (const float*)d_in[15]};

    float* ws    = (float*)d_ws;
    float* xg    = ws;                    // 8,388,608 f32  (32 imgs x 256 px x 1024)
    float* gtmp  = xg    + 8388608;       // 1,048,576
    float* cbuf  = gtmp  + 1048576;       //   262,144
    float* hs    = cbuf  + 262144;        // 2,097,152
    float* part  = hs    + 2097152;       //   262,144
    float* stats = part  + 262144;        //       512
    u16*  pad_x  = (u16*)(stats + 512);   // 32*18*18*256 = 2,654,208 fp16
    u16*  pad_h  = pad_x + 2654208;       //  4*18*18*256 =   331,776
    u16*  wTx    = pad_h + 331776;        // 1024*2304    = 2,359,296
    u16*  wTh    = wTx   + 2359296;       //                2,359,296
    // total ~63.6 MB

    hipMemsetAsync(pad_x, 0, 2654208 * sizeof(u16), stream);   // halo zeros
    hipLaunchKernelGGL(convert_x_k, dim3(2048), dim3(256), 0, stream, x0, pad_x);

    for (int l = 0; l < 3; ++l) {
        hipLaunchKernelGGL(wprep_k, dim3(72, 4), dim3(256), 0, stream, Wx[l], wTx);
        hipLaunchKernelGGL(wprep_k, dim3(72, 4), dim3(256), 0, stream, Wh[l], wTh);

        // input-to-gate conv for all 32 images: xg = conv(pad_x, Wx) + b
        hipLaunchKernelGGL((conv_mfma_k<128, 128, 0>), dim3(64, 8), dim3(256), 0, stream,
            pad_x, wTx, bb[l], (const float*)nullptr, 0L, xg);

        hipMemsetAsync(pad_h, 0, 331776 * sizeof(u16), stream);
        hipMemsetAsync(cbuf, 0, 262144 * sizeof(float), stream);

        for (int t = 0; t < TSTEPS; ++t) {
            hipLaunchKernelGGL((conv_mfma_k<64, 64, 1>), dim3(256), dim3(256), 0, stream,
                pad_h, wTh, (const float*)nullptr,
                xg + (long)t * HW * COUT, (long)TSTEPS * HW * COUT, gtmp);
            hipLaunchKernelGGL(gates_k, dim3(1024), dim3(256), 0, stream,
                gtmp, cbuf, hs, pad_h, t);
        }

        hipLaunchKernelGGL(bn_stats1_k, dim3(512), dim3(256), 0, stream, hs, part);
        hipLaunchKernelGGL(bn_stats2_k, dim3(1), dim3(256), 0, stream, part, gg[l], be[l], stats);
        hipLaunchKernelGGL(bn_apply_k, dim3(2048), dim3(256), 0, stream, hs, stats,
            (l < 2) ? pad_x : (u16*)nullptr, (l == 2) ? (float*)d_out : (float*)nullptr);
    }
}

// Round 4
// 713.227 us; speedup vs baseline: 8.3316x; 1.3962x over previous
//
#include <hip/hip_runtime.h>

// B=4, T=8, H=W=16, C=F=256, gates 4F=1024. K = 9*256 = 2304.
// Round 4: depth-4 pipelined K-loop (counted vmcnt + raw s_barrier),
// gate-interleaved N layout (n' = f*4+g) with LSTM cell fused into the
// recurrent conv epilogue (quad-transpose via shfl_xor), chunk-XOR LDS
// swizzle on both staging source and fragment reads (<=2-way conflicts).
#define HW      256
#define COUT    1024
#define TSTEPS  8
#define BN_EPS  1e-3f
#define KTOT    2304
#define KQN     72          // KTOT/32

typedef unsigned short u16;
typedef unsigned int   u32;
typedef __attribute__((ext_vector_type(8))) _Float16 v8h;  // 8 x fp16
typedef __attribute__((ext_vector_type(4))) float v4f;

__device__ __forceinline__ u16 f2h(float x) {
    _Float16 h = (_Float16)x;          // v_cvt_f16_f32, RTNE
    return *(u16*)&h;
}
__device__ __forceinline__ float hsig(float x) {
    return fminf(fmaxf(0.2f * x + 0.5f, 0.f), 1.f);
}

typedef __attribute__((address_space(1))) const unsigned int gas_u32;
typedef __attribute__((address_space(3))) unsigned int las_u32;
__device__ __forceinline__ void gl16(const void* g, void* l) {
    __builtin_amdgcn_global_load_lds((gas_u32*)g, (las_u32*)l, 16, 0, 0);
}

// ---------------------------------------------------------------------------
// Big input conv: M=8192 (32 imgs x 256 px), N'=1024 gate-interleaved,
// K=2304. BM=BN=128, 4 waves (2x2), depth-4 LDS pipeline.
// Grid 512 1-D: by = bid&7 (one N-slab per XCD), bx = bid>>3.
// ---------------------------------------------------------------------------
__global__ __launch_bounds__(256) void conv_big_k(
    const u16* __restrict__ apad,     // (32,18,18,256) fp16 zero-padded
    const u16* __restrict__ wT,       // (1024 n', 2304) fp16
    const float* __restrict__ bias,   // (1024) original n order
    float* __restrict__ out)          // (8192, 1024) n' order
{
    constexpr int BM = 128, BN = 128, AR = 32, BR = 32, ANI = 2, BNI = 2;
    constexpr int MI = 4, NI = 4;
    constexpr int BUF = (BM + BN) * 32;          // u16 per buffer
    __shared__ u16 lds[4 * BUF];                 // 64 KiB

    const int bid = blockIdx.x;
    const int by = bid & 7, bx = bid >> 3;
    const int m0 = bx * BM, n0 = by * BN;
    const int tid = threadIdx.x, lane = tid & 63, w = tid >> 6;
    const int wr = w >> 1, wc = w & 1;
    const int swz = (lane & 3) ^ ((lane >> 2) & 3) ^ ((lane >> 4) & 3);

    const char* a_src[ANI];
    #pragma unroll
    for (int i = 0; i < ANI; ++i) {
        int m = m0 + w * AR + i * 16 + (lane >> 2);
        int img = m >> 8, pix = m & 255, yy = pix >> 4, xx = pix & 15;
        a_src[i] = (const char*)apad +
                   ((((long)img * 18 + yy) * 18 + xx) * 256) * 2 + swz * 16;
    }
    const char* b_src[BNI];
    #pragma unroll
    for (int i = 0; i < BNI; ++i) {
        int n = n0 + w * BR + i * 16 + (lane >> 2);
        b_src[i] = (const char*)wT + ((long)n * KTOT) * 2 + swz * 16;
    }

    v4f acc[MI][NI];
    #pragma unroll
    for (int mi = 0; mi < MI; ++mi)
        #pragma unroll
        for (int ni = 0; ni < NI; ++ni) acc[mi][ni] = (v4f)0.f;

#define STAGE_B(J) { int j_ = (J); int dxy = j_ >> 3, c32 = j_ & 7;          \
    int dy = (dxy * 11) >> 5; int dx = dxy - dy * 3;                         \
    int aoff = ((dy * 18 + dx) * 256 + c32 * 32) * 2; int boff = j_ * 64;    \
    u16* Ab_ = lds + (j_ & 3) * BUF; u16* Bb_ = Ab_ + BM * 32;               \
    _Pragma("unroll") for (int i = 0; i < ANI; ++i)                          \
        gl16(a_src[i] + aoff, (char*)Ab_ + (w * AR + i * 16) * 64);          \
    _Pragma("unroll") for (int i = 0; i < BNI; ++i)                          \
        gl16(b_src[i] + boff, (char*)Bb_ + (w * BR + i * 16) * 64); }

#define COMPUTE_B(KQ) { u16* Ab_ = lds + ((KQ) & 3) * BUF;                   \
    u16* Bb_ = Ab_ + BM * 32; v8h af[MI], bf[NI];                            \
    _Pragma("unroll") for (int mi = 0; mi < MI; ++mi)                        \
        af[mi] = *(const v8h*)&Ab_[(wr * 64 + mi * 16 + (lane & 15)) * 32 + swz * 8]; \
    _Pragma("unroll") for (int ni = 0; ni < NI; ++ni)                        \
        bf[ni] = *(const v8h*)&Bb_[(wc * 64 + ni * 16 + (lane & 15)) * 32 + swz * 8]; \
    _Pragma("unroll") for (int mi = 0; mi < MI; ++mi)                        \
        _Pragma("unroll") for (int ni = 0; ni < NI; ++ni)                    \
            acc[mi][ni] = __builtin_amdgcn_mfma_f32_16x16x32_f16(af[mi], bf[ni], acc[mi][ni], 0, 0, 0); }

    STAGE_B(0); STAGE_B(1); STAGE_B(2);
    for (int kq = 0; kq < KQN - 3; ++kq) {
        asm volatile("s_waitcnt vmcnt(8)" ::: "memory");
        __builtin_amdgcn_s_barrier();
        __builtin_amdgcn_sched_barrier(0);
        STAGE_B(kq + 3);
        COMPUTE_B(kq);
    }
    asm volatile("s_waitcnt vmcnt(8)" ::: "memory");
    __builtin_amdgcn_s_barrier();
    __builtin_amdgcn_sched_barrier(0);
    COMPUTE_B(KQN - 3);
    asm volatile("s_waitcnt vmcnt(4)" ::: "memory");
    __builtin_amdgcn_s_barrier();
    __builtin_amdgcn_sched_barrier(0);
    COMPUTE_B(KQN - 2);
    asm volatile("s_waitcnt vmcnt(0)" ::: "memory");
    __builtin_amdgcn_s_barrier();
    __builtin_amdgcn_sched_barrier(0);
    COMPUTE_B(KQN - 1);
#undef STAGE_B
#undef COMPUTE_B

    // epilogue: + bias (remapped from n' to original n), store fp32 n'-order
    #pragma unroll
    for (int mi = 0; mi < MI; ++mi) {
        #pragma unroll
        for (int ni = 0; ni < NI; ++ni) {
            int mrow = m0 + wr * 64 + mi * 16 + ((lane >> 4) << 2);
            int ncol = n0 + wc * 64 + ni * 16 + (lane & 15);
            float b0 = bias[(ncol & 3) * 256 + (ncol >> 2)];
            #pragma unroll
            for (int r = 0; r < 4; ++r)
                out[(long)(mrow + r) * COUT + ncol] = acc[mi][ni][r] + b0;
        }
    }
}

// ---------------------------------------------------------------------------
// Recurrent conv + fused LSTM cell. M=1024 (4 imgs), N'=1024, BM=BN=64,
// depth-4 pipeline. Epilogue: quad-transpose gates, + xg, cell update,
// write cbuf/hs/pad_h(fp16, ping-pong).
// ---------------------------------------------------------------------------
__global__ __launch_bounds__(256) void rec_fused_k(
    const u16* __restrict__ ph_in,    // (4,18,18,256) fp16  h_{t-1}
    const u16* __restrict__ wT,       // (1024 n', 2304) fp16
    const float* __restrict__ xg,     // (8192, 1024) n' order (incl. bias)
    float* __restrict__ cbuf,         // (4,256,256)
    float* __restrict__ hs,           // (4,8,256,256)
    u16* __restrict__ ph_out,         // (4,18,18,256) fp16  h_t
    int t)
{
    constexpr int BM = 64, BN = 64, AR = 16, BR = 16, ANI = 1, BNI = 1;
    constexpr int MI = 2, NI = 2;
    constexpr int BUF = (BM + BN) * 32;
    __shared__ u16 lds[4 * BUF];                 // 32 KiB

    const int bid = blockIdx.x;                  // XCD swizzle: n-slices per XCD
    const int k8 = bid & 7, q = bid >> 3;
    const int by = 2 * k8 + (q >> 4), bx = q & 15;
    const int m0 = bx * BM, n0 = by * BN;
    const int tid = threadIdx.x, lane = tid & 63, w = tid >> 6;
    const int wr = w >> 1, wc = w & 1;
    const int swz = (lane & 3) ^ ((lane >> 2) & 3) ^ ((lane >> 4) & 3);

    const char* a_src[ANI];
    #pragma unroll
    for (int i = 0; i < ANI; ++i) {
        int m = m0 + w * AR + i * 16 + (lane >> 2);
        int img = m >> 8, pix = m & 255, yy = pix >> 4, xx = pix & 15;
        a_src[i] = (const char*)ph_in +
                   ((((long)img * 18 + yy) * 18 + xx) * 256) * 2 + swz * 16;
    }
    const char* b_src[BNI];
    #pragma unroll
    for (int i = 0; i < BNI; ++i) {
        int n = n0 + w * BR + i * 16 + (lane >> 2);
        b_src[i] = (const char*)wT + ((long)n * KTOT) * 2 + swz * 16;
    }

    v4f acc[MI][NI];
    #pragma unroll
    for (int mi = 0; mi < MI; ++mi)
        #pragma unroll
        for (int ni = 0; ni < NI; ++ni) acc[mi][ni] = (v4f)0.f;

#define STAGE_R(J) { int j_ = (J); int dxy = j_ >> 3, c32 = j_ & 7;          \
    int dy = (dxy * 11) >> 5; int dx = dxy - dy * 3;                         \
    int aoff = ((dy * 18 + dx) * 256 + c32 * 32) * 2; int boff = j_ * 64;    \
    u16* Ab_ = lds + (j_ & 3) * BUF; u16* Bb_ = Ab_ + BM * 32;               \
    gl16(a_src[0] + aoff, (char*)Ab_ + (w * AR) * 64);                       \
    gl16(b_src[0] + boff, (char*)Bb_ + (w * BR) * 64); }

#define COMPUTE_R(KQ) { u16* Ab_ = lds + ((KQ) & 3) * BUF;                   \
    u16* Bb_ = Ab_ + BM * 32; v8h af[MI], bf[NI];                            \
    _Pragma("unroll") for (int mi = 0; mi < MI; ++mi)                        \
        af[mi] = *(const v8h*)&Ab_[(wr * 32 + mi * 16 + (lane & 15)) * 32 + swz * 8]; \
    _Pragma("unroll") for (int ni = 0; ni < NI; ++ni)                        \
        bf[ni] = *(const v8h*)&Bb_[(wc * 32 + ni * 16 + (lane & 15)) * 32 + swz * 8]; \
    _Pragma("unroll") for (int mi = 0; mi < MI; ++mi)                        \
        _Pragma("unroll") for (int ni = 0; ni < NI; ++ni)                    \
            acc[mi][ni] = __builtin_amdgcn_mfma_f32_16x16x32_f16(af[mi], bf[ni], acc[mi][ni], 0, 0, 0); }

    STAGE_R(0); STAGE_R(1); STAGE_R(2);
    for (int kq = 0; kq < KQN - 3; ++kq) {
        asm volatile("s_waitcnt vmcnt(4)" ::: "memory");
        __builtin_amdgcn_s_barrier();
        __builtin_amdgcn_sched_barrier(0);
        STAGE_R(kq + 3);
        COMPUTE_R(kq);
    }
    asm volatile("s_waitcnt vmcnt(4)" ::: "memory");
    __builtin_amdgcn_s_barrier();
    __builtin_amdgcn_sched_barrier(0);
    COMPUTE_R(KQN - 3);
    asm volatile("s_waitcnt vmcnt(2)" ::: "memory");
    __builtin_amdgcn_s_barrier();
    __builtin_amdgcn_sched_barrier(0);
    COMPUTE_R(KQN - 2);
    asm volatile("s_waitcnt vmcnt(0)" ::: "memory");
    __builtin_amdgcn_s_barrier();
    __builtin_amdgcn_sched_barrier(0);
    COMPUTE_R(KQN - 1);
#undef STAGE_R
#undef COMPUTE_R

    // epilogue: quad-transpose (gate-lane <-> row-reg), + xg, cell update.
    const bool g0 = lane & 1, g1 = lane & 2;
    #pragma unroll
    for (int mi = 0; mi < MI; ++mi) {
        #pragma unroll
        for (int ni = 0; ni < NI; ++ni) {
            float V0 = acc[mi][ni][0], V1 = acc[mi][ni][1];
            float V2 = acc[mi][ni][2], V3 = acc[mi][ni][3];
            float x0 = __shfl_xor(V0, 1), x1 = __shfl_xor(V1, 1);
            float x2 = __shfl_xor(V2, 1), x3 = __shfl_xor(V3, 1);
            float a0 = g0 ? x1 : V0;
            float a1 = g0 ? V1 : x0;
            float a2 = g0 ? x3 : V2;
            float a3 = g0 ? V3 : x2;
            float s0 = __shfl_xor(a0, 2), s1 = __shfl_xor(a1, 2);
            float s2 = __shfl_xor(a2, 2), s3 = __shfl_xor(a3, 2);
            float Ti = g1 ? s2 : a0;   // gate i, row lane&3
            float Tf = g1 ? s3 : a1;   // gate f
            float Tc = g1 ? a2 : s0;   // gate c~
            float To = g1 ? a3 : s1;   // gate o

            int row = m0 + wr * 32 + mi * 16 + ((lane >> 4) << 2) + (lane & 3);
            int f4  = n0 + wc * 32 + ni * 16 + (lane & 12);
            int img = row >> 8, pix = row & 255, fch = f4 >> 2;
            long xrow = ((long)(img * TSTEPS + t) * HW + pix);
            const float4 xv = *(const float4*)&xg[xrow * COUT + f4];
            float pi = Ti + xv.x, pf = Tf + xv.y, pc = Tc + xv.z, po = To + xv.w;
            long cidx = (long)row * 256 + fch;
            float c = hsig(pf) * cbuf[cidx] + hsig(pi) * tanhf(pc);
            float h = hsig(po) * tanhf(c);
            cbuf[cidx] = c;
            hs[xrow * 256 + fch] = h;
            int yy = pix >> 4, xx = pix & 15;
            ph_out[(((long)img * 18 + yy + 1) * 18 + xx + 1) * 256 + fch] = f2h(h);
        }
    }
}

// ---------------------------------------------------------------------------
// weight prep: w (3,3,256,1024) fp32 -> wT (1024 n', 2304) fp16,
// n' = f*4 + g  (orig n = g*256 + f)
// ---------------------------------------------------------------------------
__global__ __launch_bounds__(256) void wprep_k(const float* __restrict__ w,
                                               u16* __restrict__ wT)
{
    int k0 = blockIdx.x * 32;
    int np = blockIdx.y * 256 + threadIdx.x;      // n' row
    int n  = (np & 3) * 256 + (np >> 2);          // original column
    u32 pk[16];
    #pragma unroll
    for (int kk = 0; kk < 32; kk += 2) {
        float a = w[(long)(k0 + kk) * COUT + n];
        float b = w[(long)(k0 + kk + 1) * COUT + n];
        pk[kk >> 1] = (u32)f2h(a) | ((u32)f2h(b) << 16);
    }
    uint4* dst = (uint4*)&wT[(long)np * KTOT + k0];
    dst[0] = make_uint4(pk[0], pk[1], pk[2], pk[3]);
    dst[1] = make_uint4(pk[4], pk[5], pk[6], pk[7]);
    dst[2] = make_uint4(pk[8], pk[9], pk[10], pk[11]);
    dst[3] = make_uint4(pk[12], pk[13], pk[14], pk[15]);
}

// ---------------------------------------------------------------------------
// convert input x (32,16,16,256) fp32 -> pad_x interior fp16
// ---------------------------------------------------------------------------
__global__ __launch_bounds__(256) void convert_x_k(const float* __restrict__ x,
                                                   u16* __restrict__ padx)
{
    int q = blockIdx.x * 256 + threadIdx.x;     // float4 index, 524288 total
    int e0 = q * 4;
    int f = e0 & 255, pix = (e0 >> 8) & 255, img = e0 >> 16;
    float4 v = ((const float4*)x)[q];
    int yy = pix >> 4, xx = pix & 15;
    long o = (((long)img * 18 + yy + 1) * 18 + xx + 1) * 256 + f;
    u32 lo = (u32)f2h(v.x) | ((u32)f2h(v.y) << 16);
    u32 hi = (u32)f2h(v.z) | ((u32)f2h(v.w) << 16);
    *(uint2*)&padx[o] = make_uint2(lo, hi);
}

// ---------------------------------------------------------------------------
// BatchNorm: deterministic two-stage stats + apply
// ---------------------------------------------------------------------------
__global__ __launch_bounds__(256) void bn_stats1_k(
    const float* __restrict__ x, float* __restrict__ partial)
{
    const int tid = threadIdx.x;
    const int blk = blockIdx.x;
    float s = 0.f, s2 = 0.f;
    const long base = (long)blk * 16 * 256;
    #pragma unroll
    for (int gi = 0; gi < 16; ++gi) {
        float v = x[base + gi * 256 + tid];
        s += v; s2 += v * v;
    }
    partial[blk * 512 + tid]       = s;
    partial[blk * 512 + 256 + tid] = s2;
}

__global__ __launch_bounds__(256) void bn_stats2_k(
    const float* __restrict__ partial, const float* __restrict__ gamma,
    const float* __restrict__ beta, float* __restrict__ stats)
{
    const int f = threadIdx.x;
    float s = 0.f, s2 = 0.f;
    for (int b = 0; b < 512; ++b) {
        s  += partial[b * 512 + f];
        s2 += partial[b * 512 + 256 + f];
    }
    const float inv_n = 1.f / 8192.f;
    float mu  = s * inv_n;
    float var = s2 * inv_n - mu * mu;
    float sc  = gamma[f] * rsqrtf(var + BN_EPS);
    stats[f]       = sc;
    stats[256 + f] = beta[f] - mu * sc;
}

// writes fp16 into pad_x interior (layers 0,1) or fp32 to d_out (layer 2)
__global__ __launch_bounds__(256) void bn_apply_k(
    const float* __restrict__ x, const float* __restrict__ stats,
    u16* __restrict__ padx, float* __restrict__ out)
{
    const int q = blockIdx.x * 256 + threadIdx.x;   // float4 index
    const int e0 = q * 4;
    const int f = e0 & 255, pix = (e0 >> 8) & 255, img = e0 >> 16;
    float4 v  = ((const float4*)x)[q];
    float4 sc = *(const float4*)(stats + f);
    float4 sh = *(const float4*)(stats + 256 + f);
    v.x = v.x * sc.x + sh.x;
    v.y = v.y * sc.y + sh.y;
    v.z = v.z * sc.z + sh.z;
    v.w = v.w * sc.w + sh.w;
    if (out) ((float4*)out)[q] = v;
    if (padx) {
        int yy = pix >> 4, xx = pix & 15;
        long o = (((long)img * 18 + yy + 1) * 18 + xx + 1) * 256 + f;
        u32 lo = (u32)f2h(v.x) | ((u32)f2h(v.y) << 16);
        u32 hi = (u32)f2h(v.z) | ((u32)f2h(v.w) << 16);
        *(uint2*)&padx[o] = make_uint2(lo, hi);
    }
}

// ---------------------------------------------------------------------------
extern "C" void kernel_launch(void* const* d_in, const int* in_sizes, int n_in,
                              void* d_out, int out_size, void* d_ws, size_t ws_size,
                              hipStream_t stream)
{
    const float* x0    = (const float*)d_in[0];
    const float* Wx[3] = {(const float*)d_in[1], (const float*)d_in[6],  (const float*)d_in[11]};
    const float* Wh[3] = {(const float*)d_in[2], (const float*)d_in[7],  (const float*)d_in[12]};
    const float* bb[3] = {(const float*)d_in[3], (const float*)d_in[8],  (const float*)d_in[13]};
    const float* gg[3] = {(const float*)d_in[4], (const float*)d_in[9],  (const float*)d_in[14]};
    const float* be[3] = {(const float*)d_in[5], (const float*)d_in[10], (const float*)d_in[15]};

    float* ws    = (float*)d_ws;
    float* xg    = ws;                    // 8,388,608 f32 (8192 x 1024, n' order)
    float* cbuf  = xg    + 8388608;       //   262,144
    float* hs    = cbuf  + 262144;        // 2,097,152
    float* part  = hs    + 2097152;       //   262,144
    float* stats = part  + 262144;        //       512
    u16*  pad_x  = (u16*)(stats + 512);   // 32*18*18*256 = 2,654,208 fp16
    u16*  pad_h  = pad_x + 2654208;       // 2 x 4*18*18*256 = 663,552 (ping-pong)
    u16*  wTx    = pad_h + 663552;        // 1024*2304 = 2,359,296
    u16*  wTh    = wTx   + 2359296;       //             2,359,296
    const long PHN = 331776;              // one pad_h buffer (u16 elems)
    // total ~60.1 MB

    hipMemsetAsync(pad_x, 0, 2654208 * sizeof(u16), stream);   // halo zeros
    hipLaunchKernelGGL(convert_x_k, dim3(2048), dim3(256), 0, stream, x0, pad_x);

    for (int l = 0; l < 3; ++l) {
        hipLaunchKernelGGL(wprep_k, dim3(72, 4), dim3(256), 0, stream, Wx[l], wTx);
        hipLaunchKernelGGL(wprep_k, dim3(72, 4), dim3(256), 0, stream, Wh[l], wTh);

        // input-to-gate conv for all 32 images (n'-order, bias folded)
        hipLaunchKernelGGL(conv_big_k, dim3(512), dim3(256), 0, stream,
            pad_x, wTx, bb[l], xg);

        hipMemsetAsync(pad_h, 0, 2 * PHN * sizeof(u16), stream);  // halos + h0
        hipMemsetAsync(cbuf, 0, 262144 * sizeof(float), stream);

        for (int t = 0; t < TSTEPS; ++t) {
            hipLaunchKernelGGL(rec_fused_k, dim3(256), dim3(256), 0, stream,
                pad_h + (t & 1) * PHN, wTh, xg, cbuf, hs,
                pad_h + ((t & 1) ^ 1) * PHN, t);
        }

        hipLaunchKernelGGL(bn_stats1_k, dim3(512), dim3(256), 0, stream, hs, part);
        hipLaunchKernelGGL(bn_stats2_k, dim3(1), dim3(256), 0, stream, part, gg[l], be[l], stats);
        hipLaunchKernelGGL(bn_apply_k, dim3(2048), dim3(256), 0, stream, hs, stats,
            (l < 2) ? pad_x : (u16*)nullptr, (l == 2) ? (float*)d_out : (float*)nullptr);
    }
}